// Round 1
// baseline (1532.578 us; speedup 1.0000x reference)
//
#include <hip/hip_runtime.h>
#include <cstdint>
#include <cstddef>

// Problem: B=4, H=16, S=2048, D=64, fp32 in/out.
// out = softmax(mask ? QK^T/8 : -1e9) @ V   ; returns (out, attn) both fp32.
// Pass1: row sums l = sum_k mask*exp(s)  (plain bf16 MFMA QK^T)
// Pass2: recompute s (bf16x3 MFMA), p = exp(s)/l -> attn (coalesced via LDS),
//        O += p@V (bf16 MFMA), O -> out.

constexpr int S_LEN  = 2048;
constexpr int D_DIM  = 64;
constexpr int NHEAD  = 16;
constexpr int NBATCH = 4;
constexpr int BHTOT  = NBATCH * NHEAD;   // 64
constexpr int QT     = 128;              // q rows per block
constexpr int KT     = 32;               // k cols per step
constexpr int NW     = 8;                // waves per block
constexpr int TPB    = NW * 64;          // 512
constexpr int NSTEP  = S_LEN / KT;       // 64
constexpr int QTILES = S_LEN / QT;       // 16
constexpr int NBLK   = BHTOT * QTILES;   // 1024

constexpr int KSTR = 72;   // LDS row stride (bf16) for K tiles (64 + 8 pad)
constexpr int VSTR = 40;   // LDS row stride (bf16) for V^T (32 + 8 pad)
constexpr int PSTR = 36;   // LDS row stride (f32) for p staging (32 + 4 pad)

using f32x4  = __attribute__((ext_vector_type(4))) float;
using bf16x8 = __attribute__((ext_vector_type(8))) short;
using i32x4  = __attribute__((ext_vector_type(4))) int;

__device__ __forceinline__ unsigned short f2bf(float f) {
  union { float f; unsigned u; } v; v.f = f;
  return (unsigned short)((v.u + 0x7fffu + ((v.u >> 16) & 1u)) >> 16);
}
__device__ __forceinline__ float bf2f(unsigned short h) {
  union { float f; unsigned u; } v; v.u = ((unsigned)h) << 16;
  return v.f;
}

#define MFMA32 __builtin_amdgcn_mfma_f32_16x16x32_bf16

// ---------------------------------------------------------------- pass 1 ----
__global__ __launch_bounds__(TPB, 2) void attn_pass1(
    const float* __restrict__ qp, const float* __restrict__ kp,
    const int* __restrict__ maskp, float* __restrict__ lp) {
  __shared__ unsigned short khi[2][KT * KSTR];

  const int pb = blockIdx.x;
  const int lb = (pb & 7) * (NBLK / 8) + (pb >> 3);   // XCD-contiguous
  const int bh = lb / QTILES;
  const int qt = lb % QTILES;
  const int bb = bh / NHEAD;

  const int tid  = threadIdx.x;
  const int w    = tid >> 6;
  const int lane = tid & 63;
  const int g    = lane >> 4;
  const int c    = lane & 15;
  const int q0   = qt * QT + w * 16;

  // Q fragments (pre-scaled by 1/sqrt(64) = 0.125, exact in fp32)
  bf16x8 qhi[2];
#pragma unroll
  for (int s = 0; s < 2; ++s) {
    const float* qr = qp + ((size_t)bh * S_LEN + q0 + c) * D_DIM + s * 32 + g * 8;
    const f32x4 a = *(const f32x4*)qr;
    const f32x4 b = *(const f32x4*)(qr + 4);
#pragma unroll
    for (int j = 0; j < 4; ++j) {
      qhi[s][j]     = (short)f2bf(a[j] * 0.125f);
      qhi[s][4 + j] = (short)f2bf(b[j] * 0.125f);
    }
  }

  // staging: LDS row p holds global k-row k0 + perm(p), perm(p)=8g+4M+r
  const int prow  = tid >> 4;           // 0..31
  const int cseg  = (tid & 15) * 4;
  const int kperm = 8 * ((prow & 15) >> 2) + 4 * (prow >> 4) + (prow & 3);
  const float* kg = kp + ((size_t)bh * S_LEN + kperm) * D_DIM + cseg;
  const int* mrow = maskp + ((size_t)bb * S_LEN + q0 + c) * S_LEN;

  f32x4 kreg = *(const f32x4*)kg;  // prefetch step 0
  float lsum = 0.f;

  for (int t = 0; t < NSTEP; ++t) {
    const int buf = t & 1;
    {
      ushort4 hh;
      hh.x = f2bf(kreg[0]); hh.y = f2bf(kreg[1]);
      hh.z = f2bf(kreg[2]); hh.w = f2bf(kreg[3]);
      *(ushort4*)&khi[buf][prow * KSTR + cseg] = hh;
    }
    __syncthreads();
    if (t + 1 < NSTEP) kreg = *(const f32x4*)(kg + (size_t)(t + 1) * KT * D_DIM);

    const int k0 = t * KT;
    const i32x4 mk0 = *(const i32x4*)(mrow + k0 + 8 * g);
    const i32x4 mk1 = *(const i32x4*)(mrow + k0 + 8 * g + 4);

    f32x4 acc0 = {0.f, 0.f, 0.f, 0.f};
    f32x4 acc1 = {0.f, 0.f, 0.f, 0.f};
#pragma unroll
    for (int s = 0; s < 2; ++s) {
      const bf16x8 a0 = *(const bf16x8*)&khi[buf][c * KSTR + s * 32 + 8 * g];
      const bf16x8 a1 = *(const bf16x8*)&khi[buf][(16 + c) * KSTR + s * 32 + 8 * g];
      acc0 = MFMA32(a0, qhi[s], acc0, 0, 0, 0);
      acc1 = MFMA32(a1, qhi[s], acc1, 0, 0, 0);
    }
#pragma unroll
    for (int r = 0; r < 4; ++r) {
      lsum += (mk0[r] != 0) ? __expf(acc0[r]) : 0.f;
      lsum += (mk1[r] != 0) ? __expf(acc1[r]) : 0.f;
    }
  }

  // lane (g,c) has partial sum for q=c over its k subset; combine the 4 groups
  lsum += __shfl_xor(lsum, 16, 64);
  lsum += __shfl_xor(lsum, 32, 64);
  if (lane < 16) lp[(size_t)bh * S_LEN + q0 + c] = lsum;
}

// ---------------------------------------------------------------- pass 2 ----
__global__ __launch_bounds__(TPB, 2) void attn_pass2(
    const float* __restrict__ qp, const float* __restrict__ kp,
    const float* __restrict__ vp, const int* __restrict__ maskp,
    const float* __restrict__ lp, float* __restrict__ outp,
    float* __restrict__ attnp) {
  __shared__ unsigned short khi[2][KT * KSTR];
  __shared__ unsigned short klo[2][KT * KSTR];
  __shared__ unsigned short vtl[2][D_DIM * VSTR];
  __shared__ float pstage[NW][16 * PSTR];

  const int pb = blockIdx.x;
  const int lb = (pb & 7) * (NBLK / 8) + (pb >> 3);
  const int bh = lb / QTILES;
  const int qt = lb % QTILES;
  const int bb = bh / NHEAD;

  const int tid  = threadIdx.x;
  const int w    = tid >> 6;
  const int lane = tid & 63;
  const int g    = lane >> 4;
  const int c    = lane & 15;
  const int q0   = qt * QT + w * 16;

  // Q hi/lo fragments (bf16x3 split of q/8)
  bf16x8 qhi[2], qlo[2];
#pragma unroll
  for (int s = 0; s < 2; ++s) {
    const float* qr = qp + ((size_t)bh * S_LEN + q0 + c) * D_DIM + s * 32 + g * 8;
    const f32x4 a = *(const f32x4*)qr;
    const f32x4 b = *(const f32x4*)(qr + 4);
#pragma unroll
    for (int j = 0; j < 4; ++j) {
      const float x0 = a[j] * 0.125f, x1 = b[j] * 0.125f;
      const unsigned short h0 = f2bf(x0), h1 = f2bf(x1);
      qhi[s][j]     = (short)h0;
      qhi[s][4 + j] = (short)h1;
      qlo[s][j]     = (short)f2bf(x0 - bf2f(h0));
      qlo[s][4 + j] = (short)f2bf(x1 - bf2f(h1));
    }
  }

  const float linv = 1.0f / lp[(size_t)bh * S_LEN + q0 + c];

  const int prow  = tid >> 4;
  const int cseg  = (tid & 15) * 4;
  const int kperm = 8 * ((prow & 15) >> 2) + 4 * (prow >> 4) + (prow & 3);
  const float* kg = kp + ((size_t)bh * S_LEN + kperm) * D_DIM + cseg;
  const float* vg = vp + ((size_t)bh * S_LEN + prow) * D_DIM + cseg;
  const int vco   = prow ^ (((tid & 15) & 3) << 3);  // k-swizzle for V^T writes
  const int* mrow = maskp + ((size_t)bb * S_LEN + q0 + c) * S_LEN;
  float* arow     = attnp + ((size_t)bh * S_LEN + q0) * S_LEN;
  float* pst      = pstage[w];

  f32x4 accO[4] = {};
  f32x4 kreg = *(const f32x4*)kg;
  f32x4 vreg = *(const f32x4*)vg;

  for (int t = 0; t < NSTEP; ++t) {
    const int buf = t & 1;
    {
      const float f0 = kreg[0], f1 = kreg[1], f2 = kreg[2], f3 = kreg[3];
      ushort4 hh, ll;
      hh.x = f2bf(f0); hh.y = f2bf(f1); hh.z = f2bf(f2); hh.w = f2bf(f3);
      ll.x = f2bf(f0 - bf2f(hh.x)); ll.y = f2bf(f1 - bf2f(hh.y));
      ll.z = f2bf(f2 - bf2f(hh.z)); ll.w = f2bf(f3 - bf2f(hh.w));
      *(ushort4*)&khi[buf][prow * KSTR + cseg] = hh;
      *(ushort4*)&klo[buf][prow * KSTR + cseg] = ll;
      unsigned short* vd = vtl[buf];
      vd[(cseg + 0) * VSTR + vco] = f2bf(vreg[0]);
      vd[(cseg + 1) * VSTR + vco] = f2bf(vreg[1]);
      vd[(cseg + 2) * VSTR + vco] = f2bf(vreg[2]);
      vd[(cseg + 3) * VSTR + vco] = f2bf(vreg[3]);
    }
    __syncthreads();
    if (t + 1 < NSTEP) {
      kreg = *(const f32x4*)(kg + (size_t)(t + 1) * KT * D_DIM);
      vreg = *(const f32x4*)(vg + (size_t)(t + 1) * KT * D_DIM);
    }

    const int k0 = t * KT;
    const i32x4 mk0 = *(const i32x4*)(mrow + k0 + 8 * g);
    const i32x4 mk1 = *(const i32x4*)(mrow + k0 + 8 * g + 4);

    // QK^T (swapped: D = K_tile x Q^T -> lane holds S[q=c][k=k0+8g+4M+r])
    f32x4 acc0 = {0.f, 0.f, 0.f, 0.f};
    f32x4 acc1 = {0.f, 0.f, 0.f, 0.f};
#pragma unroll
    for (int s = 0; s < 2; ++s) {
      const bf16x8 a0h = *(const bf16x8*)&khi[buf][c * KSTR + s * 32 + 8 * g];
      const bf16x8 a1h = *(const bf16x8*)&khi[buf][(16 + c) * KSTR + s * 32 + 8 * g];
      const bf16x8 a0l = *(const bf16x8*)&klo[buf][c * KSTR + s * 32 + 8 * g];
      const bf16x8 a1l = *(const bf16x8*)&klo[buf][(16 + c) * KSTR + s * 32 + 8 * g];
      acc0 = MFMA32(a0h, qhi[s], acc0, 0, 0, 0);
      acc0 = MFMA32(a0h, qlo[s], acc0, 0, 0, 0);
      acc0 = MFMA32(a0l, qhi[s], acc0, 0, 0, 0);
      acc1 = MFMA32(a1h, qhi[s], acc1, 0, 0, 0);
      acc1 = MFMA32(a1h, qlo[s], acc1, 0, 0, 0);
      acc1 = MFMA32(a1l, qhi[s], acc1, 0, 0, 0);
    }

    // softmax numerators, normalized probabilities
    bf16x8 pf;
    f32x4 p0v, p1v;
#pragma unroll
    for (int r = 0; r < 4; ++r) {
      const float e0 = (mk0[r] != 0) ? __expf(acc0[r]) : 0.f;
      const float e1 = (mk1[r] != 0) ? __expf(acc1[r]) : 0.f;
      const float p0 = e0 * linv, p1 = e1 * linv;
      p0v[r] = p0; p1v[r] = p1;
      pf[r]     = (short)f2bf(p0);   // A-slot j=r   -> k = k0+8g+r
      pf[4 + r] = (short)f2bf(p1);   // A-slot j=4+r -> k = k0+8g+4+r
    }
    *(f32x4*)&pst[c * PSTR + 8 * g]     = p0v;
    *(f32x4*)&pst[c * PSTR + 8 * g + 4] = p1v;

    // PV: O[q][d] += P[q][k] * V[k][d]
#pragma unroll
    for (int tt = 0; tt < 4; ++tt) {
      const bf16x8 vf =
          *(const bf16x8*)&vtl[buf][(16 * tt + c) * VSTR + 8 * (g ^ (c >> 2))];
      accO[tt] = MFMA32(pf, vf, accO[tt], 0, 0, 0);
    }

    // flush this wave's 16x32 p tile to attn (coalesced)
    {
      const int fr = lane >> 2;      // q row 0..15
      const int fc = lane & 3;       // 8-col chunk
      const f32x4 v0 = *(const f32x4*)&pst[fr * PSTR + fc * 8];
      const f32x4 v1 = *(const f32x4*)&pst[fr * PSTR + fc * 8 + 4];
      float* dst = arow + (size_t)fr * S_LEN + k0 + fc * 8;
      *(f32x4*)dst       = v0;
      *(f32x4*)(dst + 4) = v1;
    }
  }

  // epilogue: O (already normalized)
#pragma unroll
  for (int tt = 0; tt < 4; ++tt)
#pragma unroll
    for (int r = 0; r < 4; ++r)
      outp[((size_t)bh * S_LEN + q0 + 4 * g + r) * D_DIM + 16 * tt + c] =
          accO[tt][r];
}

// ---------------------------------------------------------------- launch ----
extern "C" void kernel_launch(void* const* d_in, const int* in_sizes, int n_in,
                              void* d_out, int out_size, void* d_ws,
                              size_t ws_size, hipStream_t stream) {
  const float* q    = (const float*)d_in[0];
  const float* k    = (const float*)d_in[1];
  const float* v    = (const float*)d_in[2];
  const int*   mask = (const int*)d_in[3];

  float* outp  = (float*)d_out;
  float* attnp = outp + (size_t)BHTOT * S_LEN * D_DIM;  // out first, attn second
  float* lp    = (float*)d_ws;                           // BHTOT*S floats

  attn_pass1<<<dim3(NBLK), dim3(TPB), 0, stream>>>(q, k, mask, lp);
  attn_pass2<<<dim3(NBLK), dim3(TPB), 0, stream>>>(q, k, v, mask, lp, outp, attnp);
}

// Round 6
// 1482.500 us; speedup vs baseline: 1.0338x; 1.0338x over previous
//
#include <hip/hip_runtime.h>
#include <cstdint>
#include <cstddef>

// B=4,H=16,S=2048,D=64 fp32. out = softmax(mask? QK^T/8 : -1e9) @ V ; returns (out, attn).
// prep_kv: K -> K_hi/K_lo bf16, V -> V^T bf16, stored pre-permuted + XOR-swizzled
//          in exact LDS tile image (64 rows x 128B, chunk pos = c8 ^ (row&7)).
// prep_mask: int32 mask -> bitmask (2MB, L2-resident).
// attn_main: phase A: l = sum mask*exp(s_hi); phase B: s via bf16x3, p=exp(s)/l -> attn,
//            O += p@V. Staging via global_load_lds (16B), KT=64 double-buffered.

constexpr int S_LEN  = 2048;
constexpr int D_DIM  = 64;
constexpr int NHEAD  = 16;
constexpr int NBATCH = 4;
constexpr int BHTOT  = NBATCH * NHEAD;   // 64
constexpr int QT     = 128;
constexpr int KT     = 64;
constexpr int NW     = 8;
constexpr int TPB    = NW * 64;          // 512
constexpr int NSTEP  = S_LEN / KT;       // 32
constexpr int QTILES = S_LEN / QT;       // 16
constexpr int NBLK   = BHTOT * QTILES;   // 1024
constexpr int TILE_SH = KT * D_DIM;      // 4096 ushorts = 8KB per tile

using f32x4  = __attribute__((ext_vector_type(4))) float;
using bf16x8 = __attribute__((ext_vector_type(8))) short;

__device__ __forceinline__ unsigned short f2bf(float f) {
  union { float f; unsigned u; } v; v.f = f;
  return (unsigned short)((v.u + 0x7fffu + ((v.u >> 16) & 1u)) >> 16);
}
__device__ __forceinline__ float bf2f(unsigned short h) {
  union { float f; unsigned u; } v; v.u = ((unsigned)h) << 16;
  return v.f;
}

#define MFMA32 __builtin_amdgcn_mfma_f32_16x16x32_bf16

__device__ __forceinline__ void stage16(const unsigned short* g, unsigned short* l) {
  __builtin_amdgcn_global_load_lds(
      (const __attribute__((address_space(1))) void*)g,
      (__attribute__((address_space(3))) void*)l, 16, 0, 0);
}

// ------------------------------------------------------------------ prep ----
__global__ __launch_bounds__(512) void prep_kv(
    const float* __restrict__ kp, const float* __restrict__ vp,
    unsigned short* __restrict__ khb, unsigned short* __restrict__ klb,
    unsigned short* __restrict__ vtb) {
  const int blk = blockIdx.x;          // bh*NSTEP + t
  const int bh  = blk >> 5;
  const int t   = blk & 31;
  const int tid = threadIdx.x;
  const size_t tb = (size_t)blk * TILE_SH;

  {  // K part: LDS row p holds K row t*64 + kmap(p); chunk c8 at pos c8^(p&7)
    const int p  = tid >> 3, c8 = tid & 7;
    const int p5 = p & 31, j = p >> 5;
    const int kmap = 32 * j + 8 * ((p5 & 15) >> 2) + 4 * (p5 >> 4) + (p5 & 3);
    const int d0 = (c8 >> 2) * 32 + (c8 & 3) * 8;
    const float* src = kp + ((size_t)bh * S_LEN + t * KT + kmap) * D_DIM + d0;
    const f32x4 a = *(const f32x4*)src;
    const f32x4 b = *(const f32x4*)(src + 4);
    bf16x8 hi, lo;
#pragma unroll
    for (int i = 0; i < 4; ++i) {
      unsigned short h = f2bf(a[i]);
      hi[i] = (short)h; lo[i] = (short)f2bf(a[i] - bf2f(h));
      h = f2bf(b[i]);
      hi[4 + i] = (short)h; lo[4 + i] = (short)f2bf(b[i] - bf2f(h));
    }
    const int pos = c8 ^ (p & 7);
    *(bf16x8*)&khb[tb + p * 64 + pos * 8] = hi;
    *(bf16x8*)&klb[tb + p * 64 + pos * 8] = lo;
  }
  {  // V^T part: LDS row d holds V^T[d][k-chunk hv = 4j+g], pos hv^(d&7)
    const int d = tid >> 3, hv = tid & 7;
    const int j = hv >> 2, gg = hv & 3;
    const float* vsrc = vp + ((size_t)bh * S_LEN + t * KT + 32 * j + 8 * gg) * D_DIM + d;
    bf16x8 h;
#pragma unroll
    for (int i = 0; i < 8; ++i) h[i] = (short)f2bf(vsrc[(size_t)i * D_DIM]);
    const int pos = hv ^ (d & 7);
    *(bf16x8*)&vtb[tb + d * 64 + pos * 8] = h;
  }
}

__global__ __launch_bounds__(256) void prep_mask(
    const int* __restrict__ mp, unsigned long long* __restrict__ bm) {
  const int gw = (int)((blockIdx.x * 256 + threadIdx.x) >> 6);
  const int L  = threadIdx.x & 63;
  const size_t base = (size_t)gw * 256;
  const unsigned long long w0 = __ballot(mp[base + L] != 0);
  const unsigned long long w1 = __ballot(mp[base + 64 + L] != 0);
  const unsigned long long w2 = __ballot(mp[base + 128 + L] != 0);
  const unsigned long long w3 = __ballot(mp[base + 192 + L] != 0);
  if (L == 0) {
    const size_t o = (size_t)gw * 4;
    bm[o] = w0; bm[o + 1] = w1; bm[o + 2] = w2; bm[o + 3] = w3;
  }
}

// ------------------------------------------------------------------ main ----
__global__ __launch_bounds__(TPB, 4) void attn_main(
    const float* __restrict__ qp,
    const unsigned short* __restrict__ khb_g,
    const unsigned short* __restrict__ klb_g,
    const unsigned short* __restrict__ vtb_g,
    const unsigned long long* __restrict__ bmp,
    float* __restrict__ outp, float* __restrict__ attnp) {
  __shared__ __align__(16) unsigned short skhi[2][TILE_SH];
  __shared__ __align__(16) unsigned short sklo[2][TILE_SH];
  __shared__ __align__(16) unsigned short svt[2][TILE_SH];

  const int pb = blockIdx.x;
  const int lb = (pb & 7) * (NBLK / 8) + (pb >> 3);  // XCD-contiguous
  const int bh = lb >> 4;
  const int qt = lb & 15;
  const int bb = bh >> 4;

  const int tid = threadIdx.x;
  const int w = tid >> 6, lane = tid & 63, g = lane >> 4, c = lane & 15;
  const int cx = c & 7;
  const int q0 = qt * QT + w * 16;

  // Q fragments (scaled by 0.125), hi/lo split
  bf16x8 qhi[2], qlo[2];
#pragma unroll
  for (int s = 0; s < 2; ++s) {
    const float* qr = qp + ((size_t)bh * S_LEN + q0 + c) * D_DIM + s * 32 + g * 8;
    const f32x4 a = *(const f32x4*)qr;
    const f32x4 b = *(const f32x4*)(qr + 4);
#pragma unroll
    for (int jj = 0; jj < 4; ++jj) {
      const float x0 = a[jj] * 0.125f, x1 = b[jj] * 0.125f;
      const unsigned short h0 = f2bf(x0), h1 = f2bf(x1);
      qhi[s][jj] = (short)h0;      qhi[s][4 + jj] = (short)h1;
      qlo[s][jj] = (short)f2bf(x0 - bf2f(h0));
      qlo[s][4 + jj] = (short)f2bf(x1 - bf2f(h1));
    }
  }

  const unsigned short* khb = khb_g + (size_t)bh * NSTEP * TILE_SH;
  const unsigned short* klb = klb_g + (size_t)bh * NSTEP * TILE_SH;
  const unsigned short* vtb = vtb_g + (size_t)bh * NSTEP * TILE_SH;
  const int soff = w * 512 + lane * 8;  // this lane's 16B within the tile
  const unsigned long long* brow = bmp + ((size_t)bb * S_LEN + q0 + c) * (S_LEN / 64);

  // ---------------- phase A: l ----------------
  stage16(khb + soff, &skhi[0][w * 512]);
  __syncthreads();
  float lsum = 0.f;
  unsigned long long mw = brow[0];
  for (int t = 0; t < NSTEP; ++t) {
    const int buf = t & 1;
    if (t + 1 < NSTEP)
      stage16(khb + (size_t)(t + 1) * TILE_SH + soff, &skhi[buf ^ 1][w * 512]);
    const unsigned long long mwn = brow[(t + 1 < NSTEP) ? (t + 1) : t];

    f32x4 acc[2][2] = {};
#pragma unroll
    for (int s = 0; s < 2; ++s) {
      const int pos = ((s * 4 + g) ^ cx) * 8;
#pragma unroll
      for (int j = 0; j < 2; ++j)
#pragma unroll
        for (int M = 0; M < 2; ++M) {
          const bf16x8 a = *(const bf16x8*)&skhi[buf][(32 * j + 16 * M + c) * 64 + pos];
          acc[j][M] = MFMA32(a, qhi[s], acc[j][M], 0, 0, 0);
        }
    }
#pragma unroll
    for (int j = 0; j < 2; ++j)
#pragma unroll
      for (int M = 0; M < 2; ++M)
#pragma unroll
        for (int r = 0; r < 4; ++r) {
          const int kk = 32 * j + 8 * g + 4 * M + r;
          lsum += ((mw >> kk) & 1ull) ? __expf(acc[j][M][r]) : 0.f;
        }
    __syncthreads();
    mw = mwn;
  }
  lsum += __shfl_xor(lsum, 16, 64);
  lsum += __shfl_xor(lsum, 32, 64);
  const float linv = 1.0f / lsum;

  // ---------------- phase B: attn + O ----------------
  stage16(khb + soff, &skhi[0][w * 512]);
  stage16(klb + soff, &sklo[0][w * 512]);
  stage16(vtb + soff, &svt[0][w * 512]);
  __syncthreads();
  mw = brow[0];
  float* arow = attnp + ((size_t)bh * S_LEN + q0 + c) * S_LEN;
  f32x4 accO[4] = {};

  for (int t = 0; t < NSTEP; ++t) {
    const int buf = t & 1;
    if (t + 1 < NSTEP) {
      const size_t o = (size_t)(t + 1) * TILE_SH + soff;
      stage16(khb + o, &skhi[buf ^ 1][w * 512]);
      stage16(klb + o, &sklo[buf ^ 1][w * 512]);
      stage16(vtb + o, &svt[buf ^ 1][w * 512]);
    }
    const unsigned long long mwn = brow[(t + 1 < NSTEP) ? (t + 1) : t];

    // QK^T, bf16x3
    f32x4 acc[2][2] = {};
#pragma unroll
    for (int s = 0; s < 2; ++s) {
      const int pos = ((s * 4 + g) ^ cx) * 8;
#pragma unroll
      for (int j = 0; j < 2; ++j)
#pragma unroll
        for (int M = 0; M < 2; ++M) {
          const int ro = (32 * j + 16 * M + c) * 64 + pos;
          const bf16x8 ah = *(const bf16x8*)&skhi[buf][ro];
          const bf16x8 al = *(const bf16x8*)&sklo[buf][ro];
          acc[j][M] = MFMA32(ah, qhi[s], acc[j][M], 0, 0, 0);
          acc[j][M] = MFMA32(ah, qlo[s], acc[j][M], 0, 0, 0);
          acc[j][M] = MFMA32(al, qhi[s], acc[j][M], 0, 0, 0);
        }
    }

    // softmax + attn stores + P fragments
    bf16x8 pf[2];
#pragma unroll
    for (int j = 0; j < 2; ++j)
#pragma unroll
      for (int M = 0; M < 2; ++M) {
        f32x4 pv;
#pragma unroll
        for (int r = 0; r < 4; ++r) {
          const int kk = 32 * j + 8 * g + 4 * M + r;
          const float e = ((mw >> kk) & 1ull) ? __expf(acc[j][M][r]) : 0.f;
          const float p = e * linv;
          pv[r] = p;
          pf[j][4 * M + r] = (short)f2bf(p);
        }
        *(f32x4*)(arow + t * 64 + 32 * j + 8 * g + 4 * M) = pv;
      }

    // PV
#pragma unroll
    for (int tt = 0; tt < 4; ++tt)
#pragma unroll
      for (int j = 0; j < 2; ++j) {
        const bf16x8 vf =
            *(const bf16x8*)&svt[buf][(16 * tt + c) * 64 + ((4 * j + g) ^ cx) * 8];
        accO[tt] = MFMA32(pf[j], vf, accO[tt], 0, 0, 0);
      }
    __syncthreads();
    mw = mwn;
  }

  // epilogue: out
#pragma unroll
  for (int tt = 0; tt < 4; ++tt)
#pragma unroll
    for (int r = 0; r < 4; ++r)
      outp[((size_t)bh * S_LEN + q0 + 4 * g + r) * D_DIM + 16 * tt + c] =
          accO[tt][r];
}

// ---------------------------------------------------------------- launch ----
extern "C" void kernel_launch(void* const* d_in, const int* in_sizes, int n_in,
                              void* d_out, int out_size, void* d_ws,
                              size_t ws_size, hipStream_t stream) {
  const float* q    = (const float*)d_in[0];
  const float* k    = (const float*)d_in[1];
  const float* v    = (const float*)d_in[2];
  const int*   mask = (const int*)d_in[3];

  float* outp  = (float*)d_out;
  float* attnp = outp + (size_t)BHTOT * S_LEN * D_DIM;

  unsigned short* khb = (unsigned short*)d_ws;
  const size_t tile_total = (size_t)BHTOT * NSTEP * TILE_SH;  // 8.39M ushorts
  unsigned short* klb = khb + tile_total;
  unsigned short* vtb = klb + tile_total;
  unsigned long long* bm = (unsigned long long*)(vtb + tile_total);

  prep_kv<<<dim3(BHTOT * NSTEP), dim3(512), 0, stream>>>(k, v, khb, klb, vtb);
  prep_mask<<<dim3((NBATCH * S_LEN * S_LEN) / 1024), dim3(256), 0, stream>>>(mask, bm);
  attn_main<<<dim3(NBLK), dim3(TPB), 0, stream>>>(q, khb, klb, vtb, bm, outp, attnp);
}